// Round 3
// baseline (478.544 us; speedup 1.0000x reference)
//
#include <hip/hip_runtime.h>
#include <stdint.h>

#define B_DIM 8192
#define DIN   2048
#define DOUT  8192
#define NKT   (DIN / 128)  // 16 K-tiles of 128 bytes

typedef int  v4i __attribute__((ext_vector_type(4)));
typedef char c8  __attribute__((ext_vector_type(8)));

__device__ __forceinline__ void gload_lds16(const void* g, void* l) {
  __builtin_amdgcn_global_load_lds(
      (const __attribute__((address_space(1))) void*)g,
      (__attribute__((address_space(3))) void*)l, 16, 0, 0);
}

__device__ __forceinline__ float wave_max(float m) {
#pragma unroll
  for (int off = 32; off; off >>= 1) m = fmaxf(m, __shfl_xor(m, off, 64));
  return m;
}

// ---- kernel 0: zero the two atomic absmax words ----
__global__ void k_init(unsigned int* p) {
  p[0] = 0u;
  p[1] = 0u;
}

// ---- kernel 1: global absmax of x ----
__global__ void k_absmax(const float4* __restrict__ x, int n4,
                         unsigned int* __restrict__ out_bits) {
  int idx = blockIdx.x * blockDim.x + threadIdx.x;
  int stride = gridDim.x * blockDim.x;
  float m = 0.f;
  for (int i = idx; i < n4; i += stride) {
    float4 v = x[i];
    m = fmaxf(m, fabsf(v.x));
    m = fmaxf(m, fabsf(v.y));
    m = fmaxf(m, fabsf(v.z));
    m = fmaxf(m, fabsf(v.w));
  }
  m = wave_max(m);
  if ((threadIdx.x & 63) == 0) atomicMax(out_bits, __float_as_uint(m));
}

// ---- kernel 2: quantize x to int8 (8 elems/thread) ----
__global__ void k_quant_x(const float* __restrict__ x, c8* __restrict__ xq,
                          int n8, const unsigned int* __restrict__ sa_bits) {
  int i = blockIdx.x * blockDim.x + threadIdx.x;
  if (i >= n8) return;
  float s_a = __uint_as_float(*sa_bits) / 127.0f;
  const float4* p = (const float4*)(x + (size_t)i * 8);
  float4 v0 = p[0], v1 = p[1];
  float vv[8] = {v0.x, v0.y, v0.z, v0.w, v1.x, v1.y, v1.z, v1.w};
  c8 q;
#pragma unroll
  for (int j = 0; j < 8; ++j) {
    float r = fminf(fmaxf(rintf(vv[j] / s_a), -127.f), 127.f);
    q[j] = (char)(int)r;
  }
  xq[i] = q;
}

// ---- kernel 3: per-row weight absmax + quantize (1 block / row) ----
__global__ __launch_bounds__(256) void k_quant_w(const float* __restrict__ w,
                                                 c8* __restrict__ wq,
                                                 float* __restrict__ s_w) {
  int row = blockIdx.x;
  int tid = threadIdx.x;
  const float4* wr = (const float4*)(w + (size_t)row * DIN);
  float4 v0 = wr[tid * 2], v1 = wr[tid * 2 + 1];
  float vv[8] = {v0.x, v0.y, v0.z, v0.w, v1.x, v1.y, v1.z, v1.w};
  float m = 0.f;
#pragma unroll
  for (int j = 0; j < 8; ++j) m = fmaxf(m, fabsf(vv[j]));
  m = wave_max(m);
  __shared__ float wmax[4];
  if ((tid & 63) == 0) wmax[tid >> 6] = m;
  __syncthreads();
  m = fmaxf(fmaxf(wmax[0], wmax[1]), fmaxf(wmax[2], wmax[3]));
  float s = m / 127.0f;
  if (tid == 0) s_w[row] = s;
  c8 q;
#pragma unroll
  for (int j = 0; j < 8; ++j) {
    float r = fminf(fmaxf(rintf(vv[j] / s), -127.f), 127.f);
    q[j] = (char)(int)r;
  }
  wq[(size_t)row * (DIN / 8) + tid] = q;
}

// ---- kernel 4: int8 GEMM, 256x256 tile, 8-phase, fragment-linear LDS ----
// LDS (2 slots x 64KB): slot s: A at s*65536, B at s*65536+32768.
// Region layout (per operand, per ks of 64B): [rblk(16)][kg(4)][fr(16)] 16B
// cells -> an MFMA fragment read is 64 lanes x consecutive 16B (no conflicts).
// Stage rule: a region is restaged exactly one phase AFTER its last read, so
// barrier ordering alone makes overwrites safe; vmcnt(6) at ph4/ph8
// guarantees residency 4 phases after issue.
__global__ __launch_bounds__(512, 2) void k_gemm8(
    const char* __restrict__ Aq, const char* __restrict__ Bq,
    const float* __restrict__ s_w, const float* __restrict__ bias,
    const unsigned int* __restrict__ sa_bits, float* __restrict__ out,
    unsigned int* __restrict__ omax_bits) {
  __shared__ __align__(16) char lds[131072];

  const int tid = threadIdx.x;
  const int lane = tid & 63;
  const int wave = tid >> 6;
  const int wm = wave >> 2;  // 0..1 (M)
  const int wn = wave & 3;   // 0..3 (N)

  // bijective XCD swizzle (nwg=1024, divisible by 8) + 2D decode
  const int orig = blockIdx.x;
  const int wg = (orig & 7) * (1024 >> 3) + (orig >> 3);
  const int bx = wg & 31;  // col block (DOUT/256)
  const int by = wg >> 5;  // row block (B/256)
  const int row0 = by * 256, col0 = bx * 256;

  // staging source mapping: thread t -> cell (rblk=t>>6, kg=(t>>4)&3, fr=t&15)
  const int srow = ((tid >> 6) << 4) | (tid & 15);  // row within 128-row half
  const int skb = tid & 48;                         // k-byte within 64B ks
  const char* aS = Aq + (size_t)(row0 + srow) * DIN + skb;
  const char* bS = Bq + (size_t)(col0 + srow) * DIN + skb;

  auto STAGE = [&](int kt, int slot, int isB, int ks) {
    if (kt >= NKT) kt -= 2;  // tail dummy: re-read same data (idempotent)
    const char* src = (isB ? bS : aS) + (size_t)kt * 128 + ks * 64;
    int dst = slot * 65536 + isB * 32768 + ks * 16384 + tid * 16;
    gload_lds16(src, &lds[dst]);
    gload_lds16(src + (size_t)128 * DIN, &lds[dst + 8192]);
  };

  v4i acc[2][4][4];
#pragma unroll
  for (int mh = 0; mh < 2; ++mh)
#pragma unroll
    for (int mf = 0; mf < 4; ++mf)
#pragma unroll
      for (int nf = 0; nf < 4; ++nf) acc[mh][mf][nf] = (v4i){0, 0, 0, 0};

  const int lb = lane * 16;
  v4i b_[4];

#define PHASE(SLOT, KS, MH, SKT, SSLOT, SISB, SKS, WAIT)                     \
  do {                                                                       \
    v4i a_[4];                                                               \
    _Pragma("unroll") for (int mf = 0; mf < 4; ++mf) a_[mf] =                \
        *(const v4i*)&lds[(SLOT)*65536 + (KS)*16384 +                        \
                          ((wm)*8 + (MH)*4 + mf) * 1024 + lb];               \
    if (!(MH)) {                                                             \
      _Pragma("unroll") for (int nf = 0; nf < 4; ++nf) b_[nf] =              \
          *(const v4i*)&lds[(SLOT)*65536 + 32768 + (KS)*16384 +              \
                            ((wn)*4 + nf) * 1024 + lb];                      \
    }                                                                        \
    STAGE(SKT, SSLOT, SISB, SKS);                                            \
    if (WAIT) asm volatile("s_waitcnt vmcnt(6)" ::: "memory");               \
    asm volatile("s_barrier" ::: "memory");                                  \
    __builtin_amdgcn_s_setprio(1);                                           \
    _Pragma("unroll") for (int mf = 0; mf < 4; ++mf)                         \
        _Pragma("unroll") for (int nf = 0; nf < 4; ++nf) acc[MH][mf][nf] =   \
        __builtin_amdgcn_mfma_i32_16x16x64_i8(a_[mf], b_[nf],                \
                                              acc[MH][mf][nf], 0, 0, 0);     \
    __builtin_amdgcn_s_setprio(0);                                           \
    asm volatile("s_barrier" ::: "memory");                                  \
  } while (0)

  // prologue: tile0 (slot0) fully, tile1 (slot1) minus A-ks1
  STAGE(0, 0, 1, 0);  // t0 B ks0
  STAGE(0, 0, 0, 0);  // t0 A ks0
  STAGE(0, 0, 1, 1);  // t0 B ks1
  STAGE(0, 0, 0, 1);  // t0 A ks1
  STAGE(1, 1, 1, 0);  // t1 B ks0
  STAGE(1, 1, 0, 0);  // t1 A ks0
  STAGE(1, 1, 1, 1);  // t1 B ks1
  asm volatile("s_waitcnt vmcnt(6)" ::: "memory");
  asm volatile("s_barrier" ::: "memory");

#pragma unroll 1
  for (int it = 0; it < NKT / 2; ++it) {
    const int kt2 = 2 * it + 2, kt3 = 2 * it + 3;
    PHASE(0, 0, 0, 2 * it + 1, 1, 0, 1, false);  // stage t(2it+1) A ks1
    PHASE(0, 0, 1, kt2, 0, 1, 0, false);         // stage t(2it+2) B ks0
    PHASE(0, 1, 0, kt2, 0, 0, 0, false);         // stage t(2it+2) A ks0
    PHASE(0, 1, 1, kt2, 0, 1, 1, true);          // stage t(2it+2) B ks1 +wait
    PHASE(1, 0, 0, kt2, 0, 0, 1, false);         // stage t(2it+2) A ks1
    PHASE(1, 0, 1, kt3, 1, 1, 0, false);         // stage t(2it+3) B ks0
    PHASE(1, 1, 0, kt3, 1, 0, 0, false);         // stage t(2it+3) A ks0
    PHASE(1, 1, 1, kt3, 1, 1, 1, true);          // stage t(2it+3) B ks1 +wait
  }
#undef PHASE

  // epilogue: out = (acc + round(bias/s_b)) * s_b, s_b = s_w[col]*s_a
  const int fr = lane & 15;
  float s_a = __uint_as_float(*sa_bits) / 127.0f;
  float lmax = 0.f;
#pragma unroll
  for (int nf = 0; nf < 4; ++nf) {
    int col = col0 + wn * 64 + nf * 16 + fr;
    float sw = s_w[col];
    float sb = sw * s_a;
    float bint = rintf(bias[col] / sb);
#pragma unroll
    for (int mh = 0; mh < 2; ++mh)
#pragma unroll
      for (int mf = 0; mf < 4; ++mf) {
        int rbase = row0 + wm * 128 + mh * 64 + mf * 16 + (lane >> 4) * 4;
#pragma unroll
        for (int r = 0; r < 4; ++r) {
          float o = ((float)acc[mh][mf][nf][r] + bint) * sb;
          out[(size_t)(rbase + r) * DOUT + col] = o;
          lmax = fmaxf(lmax, fabsf(o));
        }
      }
  }
  lmax = wave_max(lmax);
  if (lane == 0) atomicMax(omax_bits, __float_as_uint(lmax));
}

// ---- kernel 5: requantize output in place ----
__global__ void k_requant(float4* __restrict__ out, int n4,
                          const unsigned int* __restrict__ omax_bits) {
  float s_o = __uint_as_float(*omax_bits) / 127.0f;
  int idx = blockIdx.x * blockDim.x + threadIdx.x;
  int stride = gridDim.x * blockDim.x;
  for (int i = idx; i < n4; i += stride) {
    float4 v = out[i];
    v.x = fminf(fmaxf(rintf(v.x / s_o), -127.f), 127.f) * s_o;
    v.y = fminf(fmaxf(rintf(v.y / s_o), -127.f), 127.f) * s_o;
    v.z = fminf(fmaxf(rintf(v.z / s_o), -127.f), 127.f) * s_o;
    v.w = fminf(fmaxf(rintf(v.w / s_o), -127.f), 127.f) * s_o;
    out[i] = v;
  }
}

extern "C" void kernel_launch(void* const* d_in, const int* in_sizes, int n_in,
                              void* d_out, int out_size, void* d_ws,
                              size_t ws_size, hipStream_t stream) {
  const float* x = (const float*)d_in[0];
  const float* w = (const float*)d_in[1];
  const float* bias = (const float*)d_in[2];
  float* out = (float*)d_out;
  char* ws = (char*)d_ws;

  // ws layout:
  //   [0]   uint absmax_x_bits   [4] uint absmax_out_bits
  //   [512] float s_w[DOUT]                    (32 KB)
  //   [65536]                x_int8  (16 MB)
  //   [65536 + B*DIN]        w_int8  (16 MB)
  unsigned int* absbits = (unsigned int*)ws;
  float* s_w = (float*)(ws + 512);
  char* xq = ws + 65536;
  char* wq = ws + 65536 + (size_t)B_DIM * DIN;

  k_init<<<1, 1, 0, stream>>>(absbits);
  k_absmax<<<2048, 256, 0, stream>>>((const float4*)x, B_DIM * DIN / 4, absbits);
  k_quant_x<<<(B_DIM * DIN / 8) / 256, 256, 0, stream>>>(x, (c8*)xq,
                                                         B_DIM * DIN / 8, absbits);
  k_quant_w<<<DOUT, 256, 0, stream>>>(w, (c8*)wq, s_w);
  k_gemm8<<<1024, 512, 0, stream>>>(xq, wq, s_w, bias, absbits, out, absbits + 1);
  k_requant<<<4096, 256, 0, stream>>>((float4*)out, B_DIM * DOUT / 4, absbits + 1);
}

// Round 4
// 452.533 us; speedup vs baseline: 1.0575x; 1.0575x over previous
//
#include <hip/hip_runtime.h>
#include <stdint.h>

#define B_DIM 8192
#define DIN   2048
#define DOUT  8192
#define NKT   (DIN / 128)  // 16 K-tiles of 128 bytes

typedef int  v4i __attribute__((ext_vector_type(4)));
typedef char c8  __attribute__((ext_vector_type(8)));

__device__ __forceinline__ void gload_lds16(const void* g, void* l) {
  __builtin_amdgcn_global_load_lds(
      (const __attribute__((address_space(1))) void*)g,
      (__attribute__((address_space(3))) void*)l, 16, 0, 0);
}

__device__ __forceinline__ float wave_max(float m) {
#pragma unroll
  for (int off = 32; off; off >>= 1) m = fmaxf(m, __shfl_xor(m, off, 64));
  return m;
}

// ---- kernel 0: zero the two atomic absmax words ----
__global__ void k_init(unsigned int* p) {
  p[0] = 0u;
  p[1] = 0u;
}

// ---- kernel 1: global absmax of x ----
__global__ void k_absmax(const float4* __restrict__ x, int n4,
                         unsigned int* __restrict__ out_bits) {
  int idx = blockIdx.x * blockDim.x + threadIdx.x;
  int stride = gridDim.x * blockDim.x;
  float m = 0.f;
  for (int i = idx; i < n4; i += stride) {
    float4 v = x[i];
    m = fmaxf(m, fabsf(v.x));
    m = fmaxf(m, fabsf(v.y));
    m = fmaxf(m, fabsf(v.z));
    m = fmaxf(m, fabsf(v.w));
  }
  m = wave_max(m);
  if ((threadIdx.x & 63) == 0) atomicMax(out_bits, __float_as_uint(m));
}

// ---- kernel 2: quantize x to int8 (8 elems/thread) ----
__global__ void k_quant_x(const float* __restrict__ x, c8* __restrict__ xq,
                          int n8, const unsigned int* __restrict__ sa_bits) {
  int i = blockIdx.x * blockDim.x + threadIdx.x;
  if (i >= n8) return;
  float s_a = __uint_as_float(*sa_bits) / 127.0f;
  const float4* p = (const float4*)(x + (size_t)i * 8);
  float4 v0 = p[0], v1 = p[1];
  float vv[8] = {v0.x, v0.y, v0.z, v0.w, v1.x, v1.y, v1.z, v1.w};
  c8 q;
#pragma unroll
  for (int j = 0; j < 8; ++j) {
    float r = fminf(fmaxf(rintf(vv[j] / s_a), -127.f), 127.f);
    q[j] = (char)(int)r;
  }
  xq[i] = q;
}

// ---- kernel 3: per-row weight absmax + quantize (1 block / row) ----
__global__ __launch_bounds__(256) void k_quant_w(const float* __restrict__ w,
                                                 c8* __restrict__ wq,
                                                 float* __restrict__ s_w) {
  int row = blockIdx.x;
  int tid = threadIdx.x;
  const float4* wr = (const float4*)(w + (size_t)row * DIN);
  float4 v0 = wr[tid * 2], v1 = wr[tid * 2 + 1];
  float vv[8] = {v0.x, v0.y, v0.z, v0.w, v1.x, v1.y, v1.z, v1.w};
  float m = 0.f;
#pragma unroll
  for (int j = 0; j < 8; ++j) m = fmaxf(m, fabsf(vv[j]));
  m = wave_max(m);
  __shared__ float wmax[4];
  if ((tid & 63) == 0) wmax[tid >> 6] = m;
  __syncthreads();
  m = fmaxf(fmaxf(wmax[0], wmax[1]), fmaxf(wmax[2], wmax[3]));
  float s = m / 127.0f;
  if (tid == 0) s_w[row] = s;
  c8 q;
#pragma unroll
  for (int j = 0; j < 8; ++j) {
    float r = fminf(fmaxf(rintf(vv[j] / s), -127.f), 127.f);
    q[j] = (char)(int)r;
  }
  wq[(size_t)row * (DIN / 8) + tid] = q;
}

// ---- kernel 4: int8 GEMM, 256x256 tile, 8-phase, fragment-linear LDS ----
// LDS (2 slots x 64KB): slot s: A at s*65536, B at s*65536+32768.
// Region layout (per operand, per ks of 64B): [rblk(16)][kg(4)][fr(16)] 16B
// cells -> an MFMA fragment read is 64 lanes x consecutive 16B (no conflicts).
// Block swizzle: 2D L2 patch. XCDs tile (bx,by) as 4x2; within an XCD the 32
// concurrent CUs form an 8bx x 4by patch -> per-K-step L2 working set is
// 12 panel-slabs (384KB << 4MB), so A and B K-slabs are fetched once per XCD
// instead of B streaming 16MB/round from L3 (R3: FETCH=271MB, the real limiter).
__global__ __launch_bounds__(512, 2) void k_gemm8(
    const char* __restrict__ Aq, const char* __restrict__ Bq,
    const float* __restrict__ s_w, const float* __restrict__ bias,
    const unsigned int* __restrict__ sa_bits, float* __restrict__ out,
    unsigned int* __restrict__ omax_bits) {
  __shared__ __align__(16) char lds[131072];

  const int tid = threadIdx.x;
  const int lane = tid & 63;
  const int wave = tid >> 6;
  const int wm = wave >> 2;  // 0..1 (M)
  const int wn = wave & 3;   // 0..3 (N)

  // bijective 2D L2-patch swizzle (1024 blocks, 8 XCDs)
  const int orig = blockIdx.x;
  const int xcd = orig & 7;
  const int k = orig >> 3;                       // slot within XCD [0,128)
  const int bx = (xcd & 3) * 8 + (k & 7);        // [0,32)
  const int by = (xcd >> 2) * 16 + (k >> 3);     // [0,32)
  const int row0 = by * 256, col0 = bx * 256;

  // staging source mapping: thread t -> cell (rblk=t>>6, kg=(t>>4)&3, fr=t&15)
  const int srow = ((tid >> 6) << 4) | (tid & 15);  // row within 128-row half
  const int skb = tid & 48;                         // k-byte within 64B ks
  const char* aS = Aq + (size_t)(row0 + srow) * DIN + skb;
  const char* bS = Bq + (size_t)(col0 + srow) * DIN + skb;

  auto STAGE = [&](int kt, int slot, int isB, int ks) {
    if (kt >= NKT) kt -= 2;  // tail dummy: re-read same data (idempotent)
    const char* src = (isB ? bS : aS) + (size_t)kt * 128 + ks * 64;
    int dst = slot * 65536 + isB * 32768 + ks * 16384 + tid * 16;
    gload_lds16(src, &lds[dst]);
    gload_lds16(src + (size_t)128 * DIN, &lds[dst + 8192]);
  };

  v4i acc[2][4][4];
#pragma unroll
  for (int mh = 0; mh < 2; ++mh)
#pragma unroll
    for (int mf = 0; mf < 4; ++mf)
#pragma unroll
      for (int nf = 0; nf < 4; ++nf) acc[mh][mf][nf] = (v4i){0, 0, 0, 0};

  const int lb = lane * 16;
  v4i b_[4];

#define PHASE(SLOT, KS, MH, SKT, SSLOT, SISB, SKS, WAIT)                     \
  do {                                                                       \
    v4i a_[4];                                                               \
    _Pragma("unroll") for (int mf = 0; mf < 4; ++mf) a_[mf] =                \
        *(const v4i*)&lds[(SLOT)*65536 + (KS)*16384 +                        \
                          ((wm)*8 + (MH)*4 + mf) * 1024 + lb];               \
    if (!(MH)) {                                                             \
      _Pragma("unroll") for (int nf = 0; nf < 4; ++nf) b_[nf] =              \
          *(const v4i*)&lds[(SLOT)*65536 + 32768 + (KS)*16384 +              \
                            ((wn)*4 + nf) * 1024 + lb];                      \
    }                                                                        \
    STAGE(SKT, SSLOT, SISB, SKS);                                            \
    if (WAIT) asm volatile("s_waitcnt vmcnt(6)" ::: "memory");               \
    asm volatile("s_barrier" ::: "memory");                                  \
    __builtin_amdgcn_s_setprio(1);                                           \
    _Pragma("unroll") for (int mf = 0; mf < 4; ++mf)                         \
        _Pragma("unroll") for (int nf = 0; nf < 4; ++nf) acc[MH][mf][nf] =   \
        __builtin_amdgcn_mfma_i32_16x16x64_i8(a_[mf], b_[nf],                \
                                              acc[MH][mf][nf], 0, 0, 0);     \
    __builtin_amdgcn_s_setprio(0);                                           \
    asm volatile("s_barrier" ::: "memory");                                  \
  } while (0)

  // prologue: tile0 (slot0) fully, tile1 (slot1) minus A-ks1
  STAGE(0, 0, 1, 0);  // t0 B ks0
  STAGE(0, 0, 0, 0);  // t0 A ks0
  STAGE(0, 0, 1, 1);  // t0 B ks1
  STAGE(0, 0, 0, 1);  // t0 A ks1
  STAGE(1, 1, 1, 0);  // t1 B ks0
  STAGE(1, 1, 0, 0);  // t1 A ks0
  STAGE(1, 1, 1, 1);  // t1 B ks1
  asm volatile("s_waitcnt vmcnt(6)" ::: "memory");
  asm volatile("s_barrier" ::: "memory");

#pragma unroll 1
  for (int it = 0; it < NKT / 2; ++it) {
    const int kt2 = 2 * it + 2, kt3 = 2 * it + 3;
    PHASE(0, 0, 0, 2 * it + 1, 1, 0, 1, false);  // stage t(2it+1) A ks1
    PHASE(0, 0, 1, kt2, 0, 1, 0, false);         // stage t(2it+2) B ks0
    PHASE(0, 1, 0, kt2, 0, 0, 0, false);         // stage t(2it+2) A ks0
    PHASE(0, 1, 1, kt2, 0, 1, 1, true);          // stage t(2it+2) B ks1 +wait
    PHASE(1, 0, 0, kt2, 0, 0, 1, false);         // stage t(2it+2) A ks1
    PHASE(1, 0, 1, kt3, 1, 1, 0, false);         // stage t(2it+3) B ks0
    PHASE(1, 1, 0, kt3, 1, 0, 0, false);         // stage t(2it+3) A ks0
    PHASE(1, 1, 1, kt3, 1, 1, 1, true);          // stage t(2it+3) B ks1 +wait
  }
#undef PHASE

  // epilogue: out = (acc + round(bias/s_b)) * s_b, s_b = s_w[col]*s_a
  const int fr = lane & 15;
  float s_a = __uint_as_float(*sa_bits) / 127.0f;
  float lmax = 0.f;
#pragma unroll
  for (int nf = 0; nf < 4; ++nf) {
    int col = col0 + wn * 64 + nf * 16 + fr;
    float sw = s_w[col];
    float sb = sw * s_a;
    float bint = rintf(bias[col] / sb);
#pragma unroll
    for (int mh = 0; mh < 2; ++mh)
#pragma unroll
      for (int mf = 0; mf < 4; ++mf) {
        int rbase = row0 + wm * 128 + mh * 64 + mf * 16 + (lane >> 4) * 4;
#pragma unroll
        for (int r = 0; r < 4; ++r) {
          float o = ((float)acc[mh][mf][nf][r] + bint) * sb;
          out[(size_t)(rbase + r) * DOUT + col] = o;
          lmax = fmaxf(lmax, fabsf(o));
        }
      }
  }
  lmax = wave_max(lmax);
  if (lane == 0) atomicMax(omax_bits, __float_as_uint(lmax));
}

// ---- kernel 5: requantize output in place ----
__global__ void k_requant(float4* __restrict__ out, int n4,
                          const unsigned int* __restrict__ omax_bits) {
  float s_o = __uint_as_float(*omax_bits) / 127.0f;
  int idx = blockIdx.x * blockDim.x + threadIdx.x;
  int stride = gridDim.x * blockDim.x;
  for (int i = idx; i < n4; i += stride) {
    float4 v = out[i];
    v.x = fminf(fmaxf(rintf(v.x / s_o), -127.f), 127.f) * s_o;
    v.y = fminf(fmaxf(rintf(v.y / s_o), -127.f), 127.f) * s_o;
    v.z = fminf(fmaxf(rintf(v.z / s_o), -127.f), 127.f) * s_o;
    v.w = fminf(fmaxf(rintf(v.w / s_o), -127.f), 127.f) * s_o;
    out[i] = v;
  }
}

extern "C" void kernel_launch(void* const* d_in, const int* in_sizes, int n_in,
                              void* d_out, int out_size, void* d_ws,
                              size_t ws_size, hipStream_t stream) {
  const float* x = (const float*)d_in[0];
  const float* w = (const float*)d_in[1];
  const float* bias = (const float*)d_in[2];
  float* out = (float*)d_out;
  char* ws = (char*)d_ws;

  // ws layout:
  //   [0]   uint absmax_x_bits   [4] uint absmax_out_bits
  //   [512] float s_w[DOUT]                    (32 KB)
  //   [65536]                x_int8  (16 MB)
  //   [65536 + B*DIN]        w_int8  (16 MB)
  unsigned int* absbits = (unsigned int*)ws;
  float* s_w = (float*)(ws + 512);
  char* xq = ws + 65536;
  char* wq = ws + 65536 + (size_t)B_DIM * DIN;

  k_init<<<1, 1, 0, stream>>>(absbits);
  k_absmax<<<2048, 256, 0, stream>>>((const float4*)x, B_DIM * DIN / 4, absbits);
  k_quant_x<<<(B_DIM * DIN / 8) / 256, 256, 0, stream>>>(x, (c8*)xq,
                                                         B_DIM * DIN / 8, absbits);
  k_quant_w<<<DOUT, 256, 0, stream>>>(w, (c8*)wq, s_w);
  k_gemm8<<<1024, 512, 0, stream>>>(xq, wq, s_w, bias, absbits, out, absbits + 1);
  k_requant<<<4096, 256, 0, stream>>>((float4*)out, B_DIM * DOUT / 4, absbits + 1);
}

// Round 5
// 350.341 us; speedup vs baseline: 1.3659x; 1.2917x over previous
//
#include <hip/hip_runtime.h>
#include <stdint.h>

#define B_DIM 8192
#define DIN   2048
#define DOUT  8192
#define NKT   (DIN / 128)  // 16 K-tiles of 128 bytes

typedef int  v4i __attribute__((ext_vector_type(4)));
typedef char c8  __attribute__((ext_vector_type(8)));

__device__ __forceinline__ void gload_lds16(const void* g, void* l) {
  __builtin_amdgcn_global_load_lds(
      (const __attribute__((address_space(1))) void*)g,
      (__attribute__((address_space(3))) void*)l, 16, 0, 0);
}

__device__ __forceinline__ float wave_max(float m) {
#pragma unroll
  for (int off = 32; off; off >>= 1) m = fmaxf(m, __shfl_xor(m, off, 64));
  return m;
}

// ---- kernel 0: zero the two atomic absmax words ----
__global__ void k_init(unsigned int* p) {
  p[0] = 0u;
  p[1] = 0u;
}

// ---- kernel 1: global absmax of x (block-reduced, 1 atomic/block) ----
__global__ __launch_bounds__(256) void k_absmax(const float4* __restrict__ x,
                                                int n4,
                                                unsigned int* __restrict__ out_bits) {
  int idx = blockIdx.x * blockDim.x + threadIdx.x;
  int stride = gridDim.x * blockDim.x;
  float m = 0.f;
  for (int i = idx; i < n4; i += stride) {
    float4 v = x[i];
    m = fmaxf(m, fabsf(v.x));
    m = fmaxf(m, fabsf(v.y));
    m = fmaxf(m, fabsf(v.z));
    m = fmaxf(m, fabsf(v.w));
  }
  m = wave_max(m);
  __shared__ float red[4];
  if ((threadIdx.x & 63) == 0) red[threadIdx.x >> 6] = m;
  __syncthreads();
  if (threadIdx.x == 0) {
    m = fmaxf(fmaxf(red[0], red[1]), fmaxf(red[2], red[3]));
    atomicMax(out_bits, __float_as_uint(m));
  }
}

// ---- kernel 2: quantize x to int8 (8 elems/thread) ----
__global__ void k_quant_x(const float* __restrict__ x, c8* __restrict__ xq,
                          int n8, const unsigned int* __restrict__ sa_bits) {
  int i = blockIdx.x * blockDim.x + threadIdx.x;
  if (i >= n8) return;
  float s_a = __uint_as_float(*sa_bits) / 127.0f;
  const float4* p = (const float4*)(x + (size_t)i * 8);
  float4 v0 = p[0], v1 = p[1];
  float vv[8] = {v0.x, v0.y, v0.z, v0.w, v1.x, v1.y, v1.z, v1.w};
  c8 q;
#pragma unroll
  for (int j = 0; j < 8; ++j) {
    float r = fminf(fmaxf(rintf(vv[j] / s_a), -127.f), 127.f);
    q[j] = (char)(int)r;
  }
  xq[i] = q;
}

// ---- kernel 3: per-row weight absmax + quantize (1 block / row) ----
__global__ __launch_bounds__(256) void k_quant_w(const float* __restrict__ w,
                                                 c8* __restrict__ wq,
                                                 float* __restrict__ s_w) {
  int row = blockIdx.x;
  int tid = threadIdx.x;
  const float4* wr = (const float4*)(w + (size_t)row * DIN);
  float4 v0 = wr[tid * 2], v1 = wr[tid * 2 + 1];
  float vv[8] = {v0.x, v0.y, v0.z, v0.w, v1.x, v1.y, v1.z, v1.w};
  float m = 0.f;
#pragma unroll
  for (int j = 0; j < 8; ++j) m = fmaxf(m, fabsf(vv[j]));
  m = wave_max(m);
  __shared__ float wmax[4];
  if ((tid & 63) == 0) wmax[tid >> 6] = m;
  __syncthreads();
  m = fmaxf(fmaxf(wmax[0], wmax[1]), fmaxf(wmax[2], wmax[3]));
  float s = m / 127.0f;
  if (tid == 0) s_w[row] = s;
  c8 q;
#pragma unroll
  for (int j = 0; j < 8; ++j) {
    float r = fminf(fmaxf(rintf(vv[j] / s), -127.f), 127.f);
    q[j] = (char)(int)r;
  }
  wq[(size_t)row * (DIN / 8) + tid] = q;
}

// ---- kernel 4: int8 GEMM, 256x256, fat-phase schedule (32 phases) ----
// Memory map identical to R4 (proven): slot s (s*65536): A.ks at +ks*16384,
// B.ks at +32768+ks*16384; region = [rblk16][kg4][fr16] 16B cells (conflict-
// free ds_read_b128: 64 lanes read 1024 consecutive bytes).
// Phase(t,ks): [8 ds_read (b0-3, a_lo0-3); vmcnt(4); s_barrier;
//               STAGE 4 gload (post-barrier); 16 MFMA; 4 ds_read a_hi;
//               16 MFMA]  -- ONE barrier per phase.
// Stage rule: F0(t) stages ks1(t+1); F1(t) stages ks0(t+2). Every staged
// region's last read is >=1 barrier before the stage issue; every read's
// data was vmcnt-drained >=1 barrier before (uniform vmcnt(4), 2-phase lead).
__global__ __launch_bounds__(512, 2) void k_gemm8(
    const char* __restrict__ Aq, const char* __restrict__ Bq,
    const float* __restrict__ s_w, const float* __restrict__ bias,
    const unsigned int* __restrict__ sa_bits, float* __restrict__ out,
    unsigned int* __restrict__ omax_bits) {
  __shared__ __align__(16) char lds[131072];

  const int tid = threadIdx.x;
  const int lane = tid & 63;
  const int wave = tid >> 6;
  const int wm = wave >> 2;  // 0..1 (M)
  const int wn = wave & 3;   // 0..3 (N)

  // bijective 2D L2-patch swizzle (1024 blocks, 8 XCDs): 4bx x 2by XCD grid,
  // 8x4 patch within an XCD (R4-verified: FETCH 271->99 MB).
  const int orig = blockIdx.x;
  const int xcd = orig & 7;
  const int k = orig >> 3;
  const int bx = (xcd & 3) * 8 + (k & 7);
  const int by = (xcd >> 2) * 16 + (k >> 3);
  const int row0 = by * 256, col0 = bx * 256;

  // staging source mapping: thread t -> cell (rblk=t>>6, kg=(t>>4)&3, fr=t&15)
  const int srow = ((tid >> 6) << 4) | (tid & 15);
  const int skb = tid & 48;
  const char* aS = Aq + (size_t)(row0 + srow) * DIN + skb;
  const char* bS = Bq + (size_t)(col0 + srow) * DIN + skb;

  auto STAGE = [&](int kt, int ks) {
    if (kt >= NKT) kt -= 2;  // tail: re-stage same data (idempotent)
    int slot = kt & 1;
    const char* srcA = aS + (size_t)kt * 128 + ks * 64;
    const char* srcB = bS + (size_t)kt * 128 + ks * 64;
    int dstA = slot * 65536 + ks * 16384 + tid * 16;
    gload_lds16(srcA, &lds[dstA]);
    gload_lds16(srcA + (size_t)128 * DIN, &lds[dstA + 8192]);
    gload_lds16(srcB, &lds[dstA + 32768]);
    gload_lds16(srcB + (size_t)128 * DIN, &lds[dstA + 40960]);
  };

  v4i acc[2][4][4];
#pragma unroll
  for (int mh = 0; mh < 2; ++mh)
#pragma unroll
    for (int mf = 0; mf < 4; ++mf)
#pragma unroll
      for (int nf = 0; nf < 4; ++nf) acc[mh][mf][nf] = (v4i){0, 0, 0, 0};

  const int lb = lane * 16;

#define PHASE(SLOT, KS, SKT, SKS)                                            \
  do {                                                                       \
    const int abase = (SLOT) * 65536 + (KS) * 16384;                         \
    v4i b_[4], a_[4];                                                        \
    _Pragma("unroll") for (int nf = 0; nf < 4; ++nf) b_[nf] =                \
        *(const v4i*)&lds[abase + 32768 + (wn * 4 + nf) * 1024 + lb];        \
    _Pragma("unroll") for (int mf = 0; mf < 4; ++mf) a_[mf] =                \
        *(const v4i*)&lds[abase + (wm * 8 + mf) * 1024 + lb];                \
    asm volatile("s_waitcnt vmcnt(4)" ::: "memory");                         \
    asm volatile("s_barrier" ::: "memory");                                  \
    STAGE(SKT, SKS);                                                         \
    __builtin_amdgcn_s_setprio(1);                                           \
    _Pragma("unroll") for (int mf = 0; mf < 4; ++mf)                         \
        _Pragma("unroll") for (int nf = 0; nf < 4; ++nf) acc[0][mf][nf] =    \
        __builtin_amdgcn_mfma_i32_16x16x64_i8(a_[mf], b_[nf],                \
                                              acc[0][mf][nf], 0, 0, 0);      \
    __builtin_amdgcn_s_setprio(0);                                           \
    _Pragma("unroll") for (int mf = 0; mf < 4; ++mf) a_[mf] =                \
        *(const v4i*)&lds[abase + (wm * 8 + 4 + mf) * 1024 + lb];            \
    __builtin_amdgcn_s_setprio(1);                                           \
    _Pragma("unroll") for (int mf = 0; mf < 4; ++mf)                         \
        _Pragma("unroll") for (int nf = 0; nf < 4; ++nf) acc[1][mf][nf] =    \
        __builtin_amdgcn_mfma_i32_16x16x64_i8(a_[mf], b_[nf],                \
                                              acc[1][mf][nf], 0, 0, 0);      \
    __builtin_amdgcn_s_setprio(0);                                           \
  } while (0)

  // prologue: ks0(0), ks1(0), ks0(1); drain to leave only ks0(1) in flight
  STAGE(0, 0);
  STAGE(0, 1);
  STAGE(1, 0);
  asm volatile("s_waitcnt vmcnt(4)" ::: "memory");
  asm volatile("s_barrier" ::: "memory");

#pragma unroll 1
  for (int i = 0; i < NKT / 2; ++i) {
    const int t0 = 2 * i, t1 = 2 * i + 1;
    PHASE(0, 0, t0 + 1, 1);  // F0(t0): stage ks1(t0+1)
    PHASE(0, 1, t0 + 2, 0);  // F1(t0): stage ks0(t0+2)
    PHASE(1, 0, t1 + 1, 1);  // F0(t1): stage ks1(t1+1)
    PHASE(1, 1, t1 + 2, 0);  // F1(t1): stage ks0(t1+2)
  }
#undef PHASE

  // epilogue: out = (acc + round(bias/s_b)) * s_b, s_b = s_w[col]*s_a
  const int fr = lane & 15;
  float s_a = __uint_as_float(*sa_bits) / 127.0f;
  float lmax = 0.f;
#pragma unroll
  for (int nf = 0; nf < 4; ++nf) {
    int col = col0 + wn * 64 + nf * 16 + fr;
    float sw = s_w[col];
    float sb = sw * s_a;
    float bint = rintf(bias[col] / sb);
#pragma unroll
    for (int mh = 0; mh < 2; ++mh)
#pragma unroll
      for (int mf = 0; mf < 4; ++mf) {
        int rbase = row0 + wm * 128 + mh * 64 + mf * 16 + (lane >> 4) * 4;
#pragma unroll
        for (int r = 0; r < 4; ++r) {
          float o = ((float)acc[mh][mf][nf][r] + bint) * sb;
          out[(size_t)(rbase + r) * DOUT + col] = o;
          lmax = fmaxf(lmax, fabsf(o));
        }
      }
  }
  // block-level max reduce -> 1 atomic per block
  lmax = wave_max(lmax);
  asm volatile("s_waitcnt vmcnt(0)" ::: "memory");  // drain tail DMA into LDS
  __syncthreads();
  float* red = (float*)lds;
  if (lane == 0) red[wave] = lmax;
  __syncthreads();
  if (tid == 0) {
    float m = 0.f;
#pragma unroll
    for (int w2 = 0; w2 < 8; ++w2) m = fmaxf(m, red[w2]);
    atomicMax(omax_bits, __float_as_uint(m));
  }
}

// ---- kernel 5: requantize output in place ----
__global__ void k_requant(float4* __restrict__ out, int n4,
                          const unsigned int* __restrict__ omax_bits) {
  float s_o = __uint_as_float(*omax_bits) / 127.0f;
  int idx = blockIdx.x * blockDim.x + threadIdx.x;
  int stride = gridDim.x * blockDim.x;
  for (int i = idx; i < n4; i += stride) {
    float4 v = out[i];
    v.x = fminf(fmaxf(rintf(v.x / s_o), -127.f), 127.f) * s_o;
    v.y = fminf(fmaxf(rintf(v.y / s_o), -127.f), 127.f) * s_o;
    v.z = fminf(fmaxf(rintf(v.z / s_o), -127.f), 127.f) * s_o;
    v.w = fminf(fmaxf(rintf(v.w / s_o), -127.f), 127.f) * s_o;
    out[i] = v;
  }
}

extern "C" void kernel_launch(void* const* d_in, const int* in_sizes, int n_in,
                              void* d_out, int out_size, void* d_ws,
                              size_t ws_size, hipStream_t stream) {
  const float* x = (const float*)d_in[0];
  const float* w = (const float*)d_in[1];
  const float* bias = (const float*)d_in[2];
  float* out = (float*)d_out;
  char* ws = (char*)d_ws;

  unsigned int* absbits = (unsigned int*)ws;
  float* s_w = (float*)(ws + 512);
  char* xq = ws + 65536;
  char* wq = ws + 65536 + (size_t)B_DIM * DIN;

  k_init<<<1, 1, 0, stream>>>(absbits);
  k_absmax<<<1024, 256, 0, stream>>>((const float4*)x, B_DIM * DIN / 4, absbits);
  k_quant_x<<<(B_DIM * DIN / 8) / 256, 256, 0, stream>>>(x, (c8*)xq,
                                                         B_DIM * DIN / 8, absbits);
  k_quant_w<<<DOUT, 256, 0, stream>>>(w, (c8*)wq, s_w);
  k_gemm8<<<1024, 512, 0, stream>>>(xq, wq, s_w, bias, absbits, out, absbits + 1);
  k_requant<<<4096, 256, 0, stream>>>((float4*)out, B_DIM * DOUT / 4, absbits + 1);
}

// Round 6
// 345.581 us; speedup vs baseline: 1.3848x; 1.0138x over previous
//
#include <hip/hip_runtime.h>
#include <stdint.h>

#define B_DIM 8192
#define DIN   2048
#define DOUT  8192
#define NKT   (DIN / 128)  // 16 K-tiles of 128 bytes

typedef int  v4i __attribute__((ext_vector_type(4)));
typedef char c8  __attribute__((ext_vector_type(8)));

__device__ __forceinline__ void gload_lds16(const void* g, void* l) {
  __builtin_amdgcn_global_load_lds(
      (const __attribute__((address_space(1))) void*)g,
      (__attribute__((address_space(3))) void*)l, 16, 0, 0);
}

__device__ __forceinline__ float wave_max(float m) {
#pragma unroll
  for (int off = 32; off; off >>= 1) m = fmaxf(m, __shfl_xor(m, off, 64));
  return m;
}

// ---- kernel 0: zero the two atomic absmax words ----
__global__ void k_init(unsigned int* p) {
  p[0] = 0u;
  p[1] = 0u;
}

// ---- kernel 1: global absmax of x (block-reduced, 1 atomic/block) ----
__global__ __launch_bounds__(256) void k_absmax(const float4* __restrict__ x,
                                                int n4,
                                                unsigned int* __restrict__ out_bits) {
  int idx = blockIdx.x * blockDim.x + threadIdx.x;
  int stride = gridDim.x * blockDim.x;
  float m = 0.f;
  for (int i = idx; i < n4; i += stride) {
    float4 v = x[i];
    m = fmaxf(m, fabsf(v.x));
    m = fmaxf(m, fabsf(v.y));
    m = fmaxf(m, fabsf(v.z));
    m = fmaxf(m, fabsf(v.w));
  }
  m = wave_max(m);
  __shared__ float red[4];
  if ((threadIdx.x & 63) == 0) red[threadIdx.x >> 6] = m;
  __syncthreads();
  if (threadIdx.x == 0) {
    m = fmaxf(fmaxf(red[0], red[1]), fmaxf(red[2], red[3]));
    atomicMax(out_bits, __float_as_uint(m));
  }
}

// ---- kernel 2: quantize x to int8 (8 elems/thread) ----
__global__ void k_quant_x(const float* __restrict__ x, c8* __restrict__ xq,
                          int n8, const unsigned int* __restrict__ sa_bits) {
  int i = blockIdx.x * blockDim.x + threadIdx.x;
  if (i >= n8) return;
  float s_a = __uint_as_float(*sa_bits) / 127.0f;
  const float4* p = (const float4*)(x + (size_t)i * 8);
  float4 v0 = p[0], v1 = p[1];
  float vv[8] = {v0.x, v0.y, v0.z, v0.w, v1.x, v1.y, v1.z, v1.w};
  c8 q;
#pragma unroll
  for (int j = 0; j < 8; ++j) {
    float r = fminf(fmaxf(rintf(vv[j] / s_a), -127.f), 127.f);
    q[j] = (char)(int)r;
  }
  xq[i] = q;
}

// ---- kernel 3: per-row weight absmax + quantize (1 block / row) ----
__global__ __launch_bounds__(256) void k_quant_w(const float* __restrict__ w,
                                                 c8* __restrict__ wq,
                                                 float* __restrict__ s_w) {
  int row = blockIdx.x;
  int tid = threadIdx.x;
  const float4* wr = (const float4*)(w + (size_t)row * DIN);
  float4 v0 = wr[tid * 2], v1 = wr[tid * 2 + 1];
  float vv[8] = {v0.x, v0.y, v0.z, v0.w, v1.x, v1.y, v1.z, v1.w};
  float m = 0.f;
#pragma unroll
  for (int j = 0; j < 8; ++j) m = fmaxf(m, fabsf(vv[j]));
  m = wave_max(m);
  __shared__ float wmax[4];
  if ((tid & 63) == 0) wmax[tid >> 6] = m;
  __syncthreads();
  m = fmaxf(fmaxf(wmax[0], wmax[1]), fmaxf(wmax[2], wmax[3]));
  float s = m / 127.0f;
  if (tid == 0) s_w[row] = s;
  c8 q;
#pragma unroll
  for (int j = 0; j < 8; ++j) {
    float r = fminf(fmaxf(rintf(vv[j] / s), -127.f), 127.f);
    q[j] = (char)(int)r;
  }
  wq[(size_t)row * (DIN / 8) + tid] = q;
}

// ---- kernel 4: int8 GEMM, 256x256, fat phases + frag-prefetch pipeline ----
// Memory map (proven R4/R5): slot s (s*65536): A.ks at +ks*16384, B.ks at
// +32768+ks*16384; region layout [rblk16][kg4][fr16] 16B cells -> fragment
// ds_read_b128 = 64 lanes x 1024 consecutive bytes (0 conflicts, R5-verified).
// Pipeline (32 phases, region(P) = {slot=(P>>1)&1, ks=P&1}, 4-phase rotation):
//  phase P: vmcnt(4)  -> stage(P-2) drained => region(P+1) resident
//           s_barrier -> every wave has drained its own stage(P-2)
//           STAGE region(P+3); prefetch-read B/A_lo of region(P+1) into the
//           other frag set; read A_hi(region(P)); 32 MFMA on current set.
// Reads issue BEFORE the MFMA cluster -> LDS port runs under the matrix pipe
// (R5's exposed ~700cyc/phase of serial LDS time was the diagnosed stall).
// Hazards: region R written at P=R-3 (and R+1 for R+4); last read at R
// (A_hi), consumed pre-barrier(R+1) via lgkm wait before MFMA c2 => >=1
// barrier between every read and the next DMA write of the same region.
__global__ __launch_bounds__(512, 2) void k_gemm8(
    const char* __restrict__ Aq, const char* __restrict__ Bq,
    const float* __restrict__ s_w, const float* __restrict__ bias,
    const unsigned int* __restrict__ sa_bits, float* __restrict__ out,
    unsigned int* __restrict__ omax_bits) {
  __shared__ __align__(16) char lds[131072];

  const int tid = threadIdx.x;
  const int lane = tid & 63;
  const int wave = tid >> 6;
  const int wm = wave >> 2;  // 0..1 (M)
  const int wn = wave & 3;   // 0..3 (N)

  // bijective 2D L2-patch swizzle (R4-verified: FETCH 271->99 MB)
  const int orig = blockIdx.x;
  const int xcd = orig & 7;
  const int k = orig >> 3;
  const int bx = (xcd & 3) * 8 + (k & 7);
  const int by = (xcd >> 2) * 16 + (k >> 3);
  const int row0 = by * 256, col0 = bx * 256;

  // staging source mapping: thread t -> cell (rblk=t>>6, kg=(t>>4)&3, fr=t&15)
  const int srow = ((tid >> 6) << 4) | (tid & 15);
  const int skb = tid & 48;
  const char* aS = Aq + (size_t)(row0 + srow) * DIN + skb;
  const char* bS = Bq + (size_t)(col0 + srow) * DIN + skb;

  auto STAGE = [&](int kt, int ks) {
    if (kt >= NKT) kt -= 2;  // tail: re-stage same region/data (idempotent)
    int slot = kt & 1;
    const char* srcA = aS + (size_t)kt * 128 + ks * 64;
    const char* srcB = bS + (size_t)kt * 128 + ks * 64;
    int dstA = slot * 65536 + ks * 16384 + tid * 16;
    gload_lds16(srcA, &lds[dstA]);
    gload_lds16(srcA + (size_t)128 * DIN, &lds[dstA + 8192]);
    gload_lds16(srcB, &lds[dstA + 32768]);
    gload_lds16(srcB + (size_t)128 * DIN, &lds[dstA + 40960]);
  };

  v4i acc[2][4][4];
#pragma unroll
  for (int mh = 0; mh < 2; ++mh)
#pragma unroll
    for (int mf = 0; mf < 4; ++mf)
#pragma unroll
      for (int nf = 0; nf < 4; ++nf) acc[mh][mf][nf] = (v4i){0, 0, 0, 0};

  const int lb = lane * 16;
  v4i b0[4], al0[4], b1[4], al1[4];  // two static frag sets (rule #20)

#define PHASE(CSLOT, CKS, CUR_B, CUR_AL, NSLOT, NKS, NXT_B, NXT_AL, SKT, SKS) \
  do {                                                                        \
    asm volatile("s_waitcnt vmcnt(4)" ::: "memory");                          \
    asm volatile("s_barrier" ::: "memory");                                   \
    STAGE(SKT, SKS);                                                          \
    const int nb = (NSLOT)*65536 + (NKS)*16384;                               \
    _Pragma("unroll") for (int nf = 0; nf < 4; ++nf) NXT_B[nf] =              \
        *(const v4i*)&lds[nb + 32768 + (wn * 4 + nf) * 1024 + lb];            \
    _Pragma("unroll") for (int mf = 0; mf < 4; ++mf) NXT_AL[mf] =             \
        *(const v4i*)&lds[nb + (wm * 8 + mf) * 1024 + lb];                    \
    const int cb = (CSLOT)*65536 + (CKS)*16384;                               \
    v4i ah[4];                                                                \
    _Pragma("unroll") for (int mf = 0; mf < 4; ++mf) ah[mf] =                 \
        *(const v4i*)&lds[cb + (wm * 8 + 4 + mf) * 1024 + lb];                \
    __builtin_amdgcn_s_setprio(1);                                            \
    _Pragma("unroll") for (int mf = 0; mf < 4; ++mf)                          \
        _Pragma("unroll") for (int nf = 0; nf < 4; ++nf) acc[0][mf][nf] =     \
        __builtin_amdgcn_mfma_i32_16x16x64_i8(CUR_AL[mf], CUR_B[nf],          \
                                              acc[0][mf][nf], 0, 0, 0);       \
    _Pragma("unroll") for (int mf = 0; mf < 4; ++mf)                          \
        _Pragma("unroll") for (int nf = 0; nf < 4; ++nf) acc[1][mf][nf] =     \
        __builtin_amdgcn_mfma_i32_16x16x64_i8(ah[mf], CUR_B[nf],              \
                                              acc[1][mf][nf], 0, 0, 0);       \
    __builtin_amdgcn_s_setprio(0);                                            \
  } while (0)

  // prologue: stage regions 0,1,2; drain region0; prefetch frags(region0)
  STAGE(0, 0);
  STAGE(0, 1);
  STAGE(1, 0);
  asm volatile("s_waitcnt vmcnt(8)" ::: "memory");
  asm volatile("s_barrier" ::: "memory");
#pragma unroll
  for (int nf = 0; nf < 4; ++nf)
    b0[nf] = *(const v4i*)&lds[32768 + (wn * 4 + nf) * 1024 + lb];
#pragma unroll
  for (int mf = 0; mf < 4; ++mf)
    al0[mf] = *(const v4i*)&lds[(wm * 8 + mf) * 1024 + lb];

#pragma unroll 1
  for (int i = 0; i < NKT / 2; ++i) {
    PHASE(0, 0, b0, al0, 0, 1, b1, al1, 2 * i + 1, 1);  // P=4i
    PHASE(0, 1, b1, al1, 1, 0, b0, al0, 2 * i + 2, 0);  // P=4i+1
    PHASE(1, 0, b0, al0, 1, 1, b1, al1, 2 * i + 2, 1);  // P=4i+2
    PHASE(1, 1, b1, al1, 0, 0, b0, al0, 2 * i + 3, 0);  // P=4i+3
  }
#undef PHASE

  // epilogue: out = (acc + round(bias/s_b)) * s_b, s_b = s_w[col]*s_a
  const int fr = lane & 15;
  float s_a = __uint_as_float(*sa_bits) / 127.0f;
  float lmax = 0.f;
#pragma unroll
  for (int nf = 0; nf < 4; ++nf) {
    int col = col0 + wn * 64 + nf * 16 + fr;
    float sw = s_w[col];
    float sb = sw * s_a;
    float bint = rintf(bias[col] / sb);
#pragma unroll
    for (int mh = 0; mh < 2; ++mh)
#pragma unroll
      for (int mf = 0; mf < 4; ++mf) {
        int rbase = row0 + wm * 128 + mh * 64 + mf * 16 + (lane >> 4) * 4;
#pragma unroll
        for (int r = 0; r < 4; ++r) {
          float o = ((float)acc[mh][mf][nf][r] + bint) * sb;
          out[(size_t)(rbase + r) * DOUT + col] = o;
          lmax = fmaxf(lmax, fabsf(o));
        }
      }
  }
  // block-level max reduce -> 1 atomic per block
  lmax = wave_max(lmax);
  asm volatile("s_waitcnt vmcnt(0)" ::: "memory");  // drain tail DMA into LDS
  __syncthreads();
  float* red = (float*)lds;
  if (lane == 0) red[wave] = lmax;
  __syncthreads();
  if (tid == 0) {
    float m = 0.f;
#pragma unroll
    for (int w2 = 0; w2 < 8; ++w2) m = fmaxf(m, red[w2]);
    atomicMax(omax_bits, __float_as_uint(m));
  }
}

// ---- kernel 5: requantize output in place ----
__global__ void k_requant(float4* __restrict__ out, int n4,
                          const unsigned int* __restrict__ omax_bits) {
  float s_o = __uint_as_float(*omax_bits) / 127.0f;
  int idx = blockIdx.x * blockDim.x + threadIdx.x;
  int stride = gridDim.x * blockDim.x;
  for (int i = idx; i < n4; i += stride) {
    float4 v = out[i];
    v.x = fminf(fmaxf(rintf(v.x / s_o), -127.f), 127.f) * s_o;
    v.y = fminf(fmaxf(rintf(v.y / s_o), -127.f), 127.f) * s_o;
    v.z = fminf(fmaxf(rintf(v.z / s_o), -127.f), 127.f) * s_o;
    v.w = fminf(fmaxf(rintf(v.w / s_o), -127.f), 127.f) * s_o;
    out[i] = v;
  }
}

extern "C" void kernel_launch(void* const* d_in, const int* in_sizes, int n_in,
                              void* d_out, int out_size, void* d_ws,
                              size_t ws_size, hipStream_t stream) {
  const float* x = (const float*)d_in[0];
  const float* w = (const float*)d_in[1];
  const float* bias = (const float*)d_in[2];
  float* out = (float*)d_out;
  char* ws = (char*)d_ws;

  unsigned int* absbits = (unsigned int*)ws;
  float* s_w = (float*)(ws + 512);
  char* xq = ws + 65536;
  char* wq = ws + 65536 + (size_t)B_DIM * DIN;

  k_init<<<1, 1, 0, stream>>>(absbits);
  k_absmax<<<1024, 256, 0, stream>>>((const float4*)x, B_DIM * DIN / 4, absbits);
  k_quant_x<<<(B_DIM * DIN / 8) / 256, 256, 0, stream>>>(x, (c8*)xq,
                                                         B_DIM * DIN / 8, absbits);
  k_quant_w<<<DOUT, 256, 0, stream>>>(w, (c8*)wq, s_w);
  k_gemm8<<<1024, 512, 0, stream>>>(xq, wq, s_w, bias, absbits, out, absbits + 1);
  k_requant<<<4096, 256, 0, stream>>>((float4*)out, B_DIM * DOUT / 4, absbits + 1);
}

// Round 7
// 345.563 us; speedup vs baseline: 1.3848x; 1.0001x over previous
//
#include <hip/hip_runtime.h>
#include <stdint.h>

#define B_DIM 8192
#define DIN   2048
#define DOUT  8192
#define NKT   (DIN / 128)  // 16 K-tiles of 128 bytes

typedef int  v4i __attribute__((ext_vector_type(4)));
typedef char c8  __attribute__((ext_vector_type(8)));

__device__ __forceinline__ void gload_lds16(const void* g, void* l) {
  __builtin_amdgcn_global_load_lds(
      (const __attribute__((address_space(1))) void*)g,
      (__attribute__((address_space(3))) void*)l, 16, 0, 0);
}

__device__ __forceinline__ float wave_max(float m) {
#pragma unroll
  for (int off = 32; off; off >>= 1) m = fmaxf(m, __shfl_xor(m, off, 64));
  return m;
}

// ---- kernel 0: zero the two atomic absmax words ----
__global__ void k_init(unsigned int* p) {
  p[0] = 0u;
  p[1] = 0u;
}

// ---- kernel 1: global absmax of x (block-reduced, 1 atomic/block) ----
__global__ __launch_bounds__(256) void k_absmax(const float4* __restrict__ x,
                                                int n4,
                                                unsigned int* __restrict__ out_bits) {
  int idx = blockIdx.x * blockDim.x + threadIdx.x;
  int stride = gridDim.x * blockDim.x;
  float m = 0.f;
  for (int i = idx; i < n4; i += stride) {
    float4 v = x[i];
    m = fmaxf(m, fabsf(v.x));
    m = fmaxf(m, fabsf(v.y));
    m = fmaxf(m, fabsf(v.z));
    m = fmaxf(m, fabsf(v.w));
  }
  m = wave_max(m);
  __shared__ float red[4];
  if ((threadIdx.x & 63) == 0) red[threadIdx.x >> 6] = m;
  __syncthreads();
  if (threadIdx.x == 0) {
    m = fmaxf(fmaxf(red[0], red[1]), fmaxf(red[2], red[3]));
    atomicMax(out_bits, __float_as_uint(m));
  }
}

// ---- kernel 2: quantize x to int8 (8 elems/thread) ----
__global__ void k_quant_x(const float* __restrict__ x, c8* __restrict__ xq,
                          int n8, const unsigned int* __restrict__ sa_bits) {
  int i = blockIdx.x * blockDim.x + threadIdx.x;
  if (i >= n8) return;
  float s_a = __uint_as_float(*sa_bits) / 127.0f;
  const float4* p = (const float4*)(x + (size_t)i * 8);
  float4 v0 = p[0], v1 = p[1];
  float vv[8] = {v0.x, v0.y, v0.z, v0.w, v1.x, v1.y, v1.z, v1.w};
  c8 q;
#pragma unroll
  for (int j = 0; j < 8; ++j) {
    float r = fminf(fmaxf(rintf(vv[j] / s_a), -127.f), 127.f);
    q[j] = (char)(int)r;
  }
  xq[i] = q;
}

// ---- kernel 3: per-row weight absmax + quantize (1 block / row) ----
__global__ __launch_bounds__(256) void k_quant_w(const float* __restrict__ w,
                                                 c8* __restrict__ wq,
                                                 float* __restrict__ s_w) {
  int row = blockIdx.x;
  int tid = threadIdx.x;
  const float4* wr = (const float4*)(w + (size_t)row * DIN);
  float4 v0 = wr[tid * 2], v1 = wr[tid * 2 + 1];
  float vv[8] = {v0.x, v0.y, v0.z, v0.w, v1.x, v1.y, v1.z, v1.w};
  float m = 0.f;
#pragma unroll
  for (int j = 0; j < 8; ++j) m = fmaxf(m, fabsf(vv[j]));
  m = wave_max(m);
  __shared__ float wmax[4];
  if ((tid & 63) == 0) wmax[tid >> 6] = m;
  __syncthreads();
  m = fmaxf(fmaxf(wmax[0], wmax[1]), fmaxf(wmax[2], wmax[3]));
  float s = m / 127.0f;
  if (tid == 0) s_w[row] = s;
  c8 q;
#pragma unroll
  for (int j = 0; j < 8; ++j) {
    float r = fminf(fmaxf(rintf(vv[j] / s), -127.f), 127.f);
    q[j] = (char)(int)r;
  }
  wq[(size_t)row * (DIN / 8) + tid] = q;
}

// ---- kernel 4: int8 GEMM, 256x256, faithful m201 8-phase 2-barrier port ----
// Byte-identical geometry to m201 bf16: BK=128B/row K-tile, 256^2 tile,
// 8 waves (2M x 4N), per-wave C 128x64, LDS 128KB (2 slots x {A 32KB | B 32KB}).
// Regions: (slot,op,ks) 16KB at slot*65536 + op*32768 + ks*16384, layout
// [rblk16][kg4][fr16] 16B cells -> frag ds_read = 64 lanes x consecutive 16B
// (0 conflicts, R5-verified). Stage unit = one region = 2 gload_lds16/thread,
// linear dst (tid*16 / +8192).
// Phase p: {8 or 4 ds_read; stage 1 unit; [vmcnt(6) @p4,p8]; s_barrier;
//           lgkmcnt(0)+sched_barrier; setprio1; 16 MFMA; setprio0; s_barrier}
// Stage calendar (iter i: t0=2i slot0, t1=2i+1 slot1, t2,t3 next):
//   p1:A1(t1) p2:B0(t2) p3:A0(t2) p4:B1(t2)+v6 p5:A1(t2) p6:B0(t3) p7:A0(t3)
//   p8:B1(t3)+v6.  FIFO check: vmcnt(6)@p4 confirms {B0,A0,B1(prev iter),A1@p1}
//   = all t1 units, 2 barriers before first t1 read (p5). vmcnt(6)@p8 confirms
//   p2..p5 = all t2 units before p1'. Every restage >=1 barrier after its
//   region's last read (B0:p1->p2, A0:p2->p3, B1:p3->p4, A1:p4->p5; slot1
//   analogous at p5..p8->p6..p1'). Tail kt>=NKT re-stages kt-2 (same slot,
//   same bytes, same ordering guarantees).
__global__ __launch_bounds__(512, 2) void k_gemm8(
    const char* __restrict__ Aq, const char* __restrict__ Bq,
    const float* __restrict__ s_w, const float* __restrict__ bias,
    const unsigned int* __restrict__ sa_bits, float* __restrict__ out,
    unsigned int* __restrict__ omax_bits) {
  __shared__ __align__(16) char lds[131072];

  const int tid = threadIdx.x;
  const int lane = tid & 63;
  const int wave = tid >> 6;
  const int wm = wave >> 2;  // 0..1 (M)
  const int wn = wave & 3;   // 0..3 (N)

  // bijective 2D L2-patch swizzle (R4-verified: FETCH 271->99 MB)
  const int orig = blockIdx.x;
  const int xcd = orig & 7;
  const int k = orig >> 3;
  const int bx = (xcd & 3) * 8 + (k & 7);
  const int by = (xcd >> 2) * 16 + (k >> 3);
  const int row0 = by * 256, col0 = bx * 256;

  // staging source mapping: thread t -> cell (rblk=t>>6, kg=(t>>4)&3, fr=t&15)
  const int srow = ((tid >> 6) << 4) | (tid & 15);
  const int skb = tid & 48;
  const char* aS = Aq + (size_t)(row0 + srow) * DIN + skb;
  const char* bS = Bq + (size_t)(col0 + srow) * DIN + skb;

  // stage one (op,ks) region of K-tile kt into slot kt&1 (2 gloads)
  auto STAGE = [&](int kt, int isB, int ks) {
    if (kt >= NKT) kt -= 2;  // tail: same slot, same bytes
    const int slot = kt & 1;
    const char* src = (isB ? bS : aS) + (size_t)kt * 128 + ks * 64;
    const int dst = slot * 65536 + isB * 32768 + ks * 16384 + tid * 16;
    gload_lds16(src, &lds[dst]);
    gload_lds16(src + (size_t)128 * DIN, &lds[dst + 8192]);
  };

  v4i acc[2][4][4];
#pragma unroll
  for (int mh = 0; mh < 2; ++mh)
#pragma unroll
    for (int mf = 0; mf < 4; ++mf)
#pragma unroll
      for (int nf = 0; nf < 4; ++nf) acc[mh][mf][nf] = (v4i){0, 0, 0, 0};

  const int lb = lane * 16;
  v4i b_[4];  // persists across the (mh0, mh1) phase pair

#define PH(SLOT, KS, MH, SKT, SISB, SKS, WAITV)                              \
  do {                                                                       \
    v4i a_[4];                                                               \
    const int ab =                                                           \
        (SLOT) * 65536 + (KS) * 16384 + (wm * 8 + (MH) * 4) * 1024 + lb;     \
    _Pragma("unroll") for (int mf = 0; mf < 4; ++mf) a_[mf] =                \
        *(const v4i*)&lds[ab + mf * 1024];                                   \
    if (!(MH)) {                                                             \
      const int bb =                                                         \
          (SLOT) * 65536 + 32768 + (KS) * 16384 + (wn * 4) * 1024 + lb;      \
      _Pragma("unroll") for (int nf = 0; nf < 4; ++nf) b_[nf] =              \
          *(const v4i*)&lds[bb + nf * 1024];                                 \
    }                                                                        \
    STAGE(SKT, SISB, SKS);                                                   \
    if (WAITV) asm volatile("s_waitcnt vmcnt(6)" ::: "memory");              \
    asm volatile("s_barrier" ::: "memory");                                  \
    asm volatile("s_waitcnt lgkmcnt(0)" ::: "memory");                       \
    __builtin_amdgcn_sched_barrier(0);                                       \
    __builtin_amdgcn_s_setprio(1);                                           \
    _Pragma("unroll") for (int mf = 0; mf < 4; ++mf)                         \
        _Pragma("unroll") for (int nf = 0; nf < 4; ++nf) acc[MH][mf][nf] =   \
        __builtin_amdgcn_mfma_i32_16x16x64_i8(a_[mf], b_[nf],                \
                                              acc[MH][mf][nf], 0, 0, 0);     \
    __builtin_amdgcn_s_setprio(0);                                           \
    asm volatile("s_barrier" ::: "memory");                                  \
  } while (0)

  // prologue: t0 fully (4 units), t1 minus A1 (issued, unconfirmed);
  // vmcnt(6) confirms exactly t0's 8 loads (14 outstanding -> keep 6).
  STAGE(0, 1, 0);  // t0 B0
  STAGE(0, 0, 0);  // t0 A0
  STAGE(0, 1, 1);  // t0 B1
  STAGE(0, 0, 1);  // t0 A1
  STAGE(1, 1, 0);  // t1 B0
  STAGE(1, 0, 0);  // t1 A0
  STAGE(1, 1, 1);  // t1 B1
  asm volatile("s_waitcnt vmcnt(6)" ::: "memory");
  asm volatile("s_barrier" ::: "memory");

#pragma unroll 1
  for (int i = 0; i < NKT / 2; ++i) {
    const int t1 = 2 * i + 1, t2 = 2 * i + 2, t3 = 2 * i + 3;
    PH(0, 0, 0, t1, 0, 1, false);  // p1: stage A1(t1)
    PH(0, 0, 1, t2, 1, 0, false);  // p2: stage B0(t2)
    PH(0, 1, 0, t2, 0, 0, false);  // p3: stage A0(t2)
    PH(0, 1, 1, t2, 1, 1, true);   // p4: stage B1(t2), vmcnt(6)
    PH(1, 0, 0, t2, 0, 1, false);  // p5: stage A1(t2)
    PH(1, 0, 1, t3, 1, 0, false);  // p6: stage B0(t3)
    PH(1, 1, 0, t3, 0, 0, false);  // p7: stage A0(t3)
    PH(1, 1, 1, t3, 1, 1, true);   // p8: stage B1(t3), vmcnt(6)
  }
#undef PH

  // epilogue: out = (acc + round(bias/s_b)) * s_b, s_b = s_w[col]*s_a
  const int fr = lane & 15;
  float s_a = __uint_as_float(*sa_bits) / 127.0f;
  float lmax = 0.f;
#pragma unroll
  for (int nf = 0; nf < 4; ++nf) {
    int col = col0 + wn * 64 + nf * 16 + fr;
    float sw = s_w[col];
    float sb = sw * s_a;
    float bint = rintf(bias[col] / sb);
#pragma unroll
    for (int mh = 0; mh < 2; ++mh)
#pragma unroll
      for (int mf = 0; mf < 4; ++mf) {
        int rbase = row0 + wm * 128 + mh * 64 + mf * 16 + (lane >> 4) * 4;
#pragma unroll
        for (int r = 0; r < 4; ++r) {
          float o = ((float)acc[mh][mf][nf][r] + bint) * sb;
          out[(size_t)(rbase + r) * DOUT + col] = o;
          lmax = fmaxf(lmax, fabsf(o));
        }
      }
  }
  // block-level max reduce -> 1 atomic per block
  lmax = wave_max(lmax);
  asm volatile("s_waitcnt vmcnt(0)" ::: "memory");  // drain tail DMA into LDS
  __syncthreads();
  float* red = (float*)lds;
  if (lane == 0) red[wave] = lmax;
  __syncthreads();
  if (tid == 0) {
    float m = 0.f;
#pragma unroll
    for (int w2 = 0; w2 < 8; ++w2) m = fmaxf(m, red[w2]);
    atomicMax(omax_bits, __float_as_uint(m));
  }
}

// ---- kernel 5: requantize output in place ----
__global__ void k_requant(float4* __restrict__ out, int n4,
                          const unsigned int* __restrict__ omax_bits) {
  float s_o = __uint_as_float(*omax_bits) / 127.0f;
  int idx = blockIdx.x * blockDim.x + threadIdx.x;
  int stride = gridDim.x * blockDim.x;
  for (int i = idx; i < n4; i += stride) {
    float4 v = out[i];
    v.x = fminf(fmaxf(rintf(v.x / s_o), -127.f), 127.f) * s_o;
    v.y = fminf(fmaxf(rintf(v.y / s_o), -127.f), 127.f) * s_o;
    v.z = fminf(fmaxf(rintf(v.z / s_o), -127.f), 127.f) * s_o;
    v.w = fminf(fmaxf(rintf(v.w / s_o), -127.f), 127.f) * s_o;
    out[i] = v;
  }
}

extern "C" void kernel_launch(void* const* d_in, const int* in_sizes, int n_in,
                              void* d_out, int out_size, void* d_ws,
                              size_t ws_size, hipStream_t stream) {
  const float* x = (const float*)d_in[0];
  const float* w = (const float*)d_in[1];
  const float* bias = (const float*)d_in[2];
  float* out = (float*)d_out;
  char* ws = (char*)d_ws;

  unsigned int* absbits = (unsigned int*)ws;
  float* s_w = (float*)(ws + 512);
  char* xq = ws + 65536;
  char* wq = ws + 65536 + (size_t)B_DIM * DIN;

  k_init<<<1, 1, 0, stream>>>(absbits);
  k_absmax<<<1024, 256, 0, stream>>>((const float4*)x, B_DIM * DIN / 4, absbits);
  k_quant_x<<<(B_DIM * DIN / 8) / 256, 256, 0, stream>>>(x, (c8*)xq,
                                                         B_DIM * DIN / 8, absbits);
  k_quant_w<<<DOUT, 256, 0, stream>>>(w, (c8*)wq, s_w);
  k_gemm8<<<1024, 512, 0, stream>>>(xq, wq, s_w, bias, absbits, out, absbits + 1);
  k_requant<<<4096, 256, 0, stream>>>((float4*)out, B_DIM * DOUT / 4, absbits + 1);
}